// Round 1
// baseline (511.224 us; speedup 1.0000x reference)
//
#include <hip/hip_runtime.h>

#define EPS 0.001f
#define HW_POS 1024          // 32*32 spatial positions per image
#define NCH 256              // channels
#define NCG 64               // channel groups of 4 (float4)
#define NB 256               // batch
#define NP 4                 // partitions
#define PS 64                // images per partition
#define SPLIT 4              // blocks per image
#define POS_PER_BLOCK (HW_POS / SPLIT)   // 256 positions per block
#define N_PER_PC 65536.0f    // PS * HW_POS elements per (partition, channel)

// ---------------- Kernel 1: per (image, quarter) partial sums ----------------
// grid = NB*SPLIT blocks, 256 threads. Thread t: cg = t&63 (4 channels), wave
// id = t>>6 picks spatial phase. Each wave loads 64 consecutive float4 = 1 KiB
// per instruction (perfectly coalesced).
__global__ __launch_bounds__(256) void k_partial(const float4* __restrict__ x,
                                                 float4* __restrict__ psum,
                                                 float4* __restrict__ psq) {
    const int slot  = blockIdx.x;        // b*SPLIT + chunk
    const int b     = slot >> 2;
    const int chunk = slot & (SPLIT - 1);
    const int t     = threadIdx.x;
    const int cg    = t & 63;
    const int srow  = t >> 6;            // 0..3 (== wave id)

    const float4* xb = x + (size_t)b * (HW_POS * NCG);
    const int s0 = chunk * POS_PER_BLOCK;

    float4 s = make_float4(0.f, 0.f, 0.f, 0.f);
    float4 q = make_float4(0.f, 0.f, 0.f, 0.f);
    #pragma unroll 4
    for (int si = s0 + srow; si < s0 + POS_PER_BLOCK; si += 4) {
        float4 v = xb[(size_t)si * NCG + cg];
        s.x += v.x; s.y += v.y; s.z += v.z; s.w += v.w;
        q.x += v.x * v.x; q.y += v.y * v.y; q.z += v.z * v.z; q.w += v.w * v.w;
    }

    __shared__ float4 ls[4][64];
    __shared__ float4 lq[4][64];
    ls[srow][cg] = s;
    lq[srow][cg] = q;
    __syncthreads();

    if (srow == 0) {
        float4 a0 = ls[0][cg], a1 = ls[1][cg], a2 = ls[2][cg], a3 = ls[3][cg];
        float4 b0 = lq[0][cg], b1 = lq[1][cg], b2 = lq[2][cg], b3 = lq[3][cg];
        float4 ts = make_float4(a0.x + a1.x + a2.x + a3.x,
                                a0.y + a1.y + a2.y + a3.y,
                                a0.z + a1.z + a2.z + a3.z,
                                a0.w + a1.w + a2.w + a3.w);
        float4 tq = make_float4(b0.x + b1.x + b2.x + b3.x,
                                b0.y + b1.y + b2.y + b3.y,
                                b0.z + b1.z + b2.z + b3.z,
                                b0.w + b1.w + b2.w + b3.w);
        psum[(size_t)slot * NCG + cg] = ts;
        psq [(size_t)slot * NCG + cg] = tq;
    }
}

// ---------------- Kernel 2: fold partials through perm -> scale/shift -------
// grid = NP blocks, NCH threads. Thread (p, c) sums the 64*SPLIT partial slots
// of its partition, computes fused affine coefficients.
__global__ __launch_bounds__(256) void k_finalize(const float* __restrict__ psum,
                                                  const float* __restrict__ psq,
                                                  const float* __restrict__ gamma,
                                                  const float* __restrict__ beta,
                                                  const int* __restrict__ perm,
                                                  float* __restrict__ scale,
                                                  float* __restrict__ shift) {
    const int p = blockIdx.x;
    const int c = threadIdx.x;

    float s = 0.f, q = 0.f;
    for (int j = 0; j < PS; ++j) {
        const int b = perm[p * PS + j];
        #pragma unroll
        for (int k = 0; k < SPLIT; ++k) {
            const int slot = b * SPLIT + k;
            s += psum[(size_t)slot * NCH + c];
            q += psq [(size_t)slot * NCH + c];
        }
    }
    const float mean = s * (1.0f / N_PER_PC);
    const float var  = q * (1.0f / N_PER_PC) - mean * mean;
    const float inv  = rsqrtf(var + EPS);
    const float g    = gamma[p * NCH + c];
    const float sc   = g * inv;
    scale[p * NCH + c] = sc;
    shift[p * NCH + c] = beta[p * NCH + c] - mean * sc;
}

// ---------------- Kernel 3: normalize ----------------------------------------
// grid indexed by shuffled position j (so partition is just j>>6), but reads
// and writes image b = perm[j] in place-order — the shuffle/unshuffle cancels.
__global__ __launch_bounds__(256) void k_norm(const float4* __restrict__ x,
                                              const float4* __restrict__ scale4,
                                              const float4* __restrict__ shift4,
                                              const int* __restrict__ perm,
                                              float4* __restrict__ out) {
    const int blk   = blockIdx.x;        // j*SPLIT + chunk
    const int j     = blk >> 2;
    const int chunk = blk & (SPLIT - 1);
    const int b     = perm[j];
    const int p     = j >> 6;            // j / PS
    const int t     = threadIdx.x;
    const int cg    = t & 63;
    const int srow  = t >> 6;

    const float4 sc = scale4[p * NCG + cg];
    const float4 sh = shift4[p * NCG + cg];

    const float4* xb = x   + (size_t)b * (HW_POS * NCG);
    float4*       ob = (float4*)out + (size_t)b * (HW_POS * NCG);
    const int s0 = chunk * POS_PER_BLOCK;

    #pragma unroll 4
    for (int si = s0 + srow; si < s0 + POS_PER_BLOCK; si += 4) {
        float4 v = xb[(size_t)si * NCG + cg];
        v.x = v.x * sc.x + sh.x;
        v.y = v.y * sc.y + sh.y;
        v.z = v.z * sc.z + sh.z;
        v.w = v.w * sc.w + sh.w;
        ob[(size_t)si * NCG + cg] = v;
    }
}

extern "C" void kernel_launch(void* const* d_in, const int* in_sizes, int n_in,
                              void* d_out, int out_size, void* d_ws, size_t ws_size,
                              hipStream_t stream) {
    const float* x     = (const float*)d_in[0];
    const float* gamma = (const float*)d_in[1];
    const float* beta  = (const float*)d_in[2];
    const int*   perm  = (const int*)d_in[3];
    float* out = (float*)d_out;

    // Workspace layout (all fully written before read; no zero-init needed):
    //   psum : NB*SPLIT slots * NCH floats = 1 MiB
    //   psq  : 1 MiB
    //   scale: NP*NCH floats = 4 KiB
    //   shift: 4 KiB
    char* ws = (char*)d_ws;
    float* psum  = (float*)(ws);
    float* psq   = (float*)(ws + (size_t)NB * SPLIT * NCH * sizeof(float));
    float* scale = (float*)(ws + 2 * (size_t)NB * SPLIT * NCH * sizeof(float));
    float* shift = scale + NP * NCH;

    k_partial<<<NB * SPLIT, 256, 0, stream>>>((const float4*)x,
                                              (float4*)psum, (float4*)psq);
    k_finalize<<<NP, NCH, 0, stream>>>(psum, psq, gamma, beta, perm, scale, shift);
    k_norm<<<NB * SPLIT, 256, 0, stream>>>((const float4*)x,
                                           (const float4*)scale, (const float4*)shift,
                                           perm, (float4*)out);
}

// Round 2
// 507.161 us; speedup vs baseline: 1.0080x; 1.0080x over previous
//
#include <hip/hip_runtime.h>

#define EPS 0.001f
#define HW_POS 1024          // 32*32 spatial positions per image
#define NCH 256              // channels
#define NCG 64               // channel groups of 4 (float4)
#define NB 256               // batch
#define NP 4                 // partitions
#define PS 64                // images per partition
#define SPLIT 4              // blocks per image
#define POS_PER_BLOCK (HW_POS / SPLIT)   // 256 positions per block
#define N_PER_PC 65536.0f    // PS * HW_POS elements per (partition, channel)

// ---------------- Kernel 0: zero the 8 KB accumulator region -----------------
__global__ __launch_bounds__(256) void k_zero(float* __restrict__ acc) {
    // 2 * NP * NCH = 2048 floats
    const int i = threadIdx.x;
    #pragma unroll
    for (int k = 0; k < 8; ++k) acc[k * 256 + i] = 0.f;
}

// ---------------- Kernel 1: per-(partition,channel) sums via atomics ---------
// grid = NB*SPLIT blocks indexed by SHUFFLED position j (so p = j>>6), 256
// threads. Thread t: cg = t&63 (float4 channel group), wave id t>>6 = spatial
// phase. Each wave-load is 64 consecutive float4 = 1 KiB, perfectly coalesced.
// After LDS reduce, wave 0 does 512 fp32 atomicAdds into acc[p][c].
__global__ __launch_bounds__(256) void k_partial(const float4* __restrict__ x,
                                                 const int* __restrict__ perm,
                                                 float* __restrict__ asum,
                                                 float* __restrict__ asq) {
    const int slot  = blockIdx.x;        // j*SPLIT + chunk
    const int j     = slot >> 2;
    const int chunk = slot & (SPLIT - 1);
    const int b     = perm[j];
    const int p     = j >> 6;            // partition
    const int t     = threadIdx.x;
    const int cg    = t & 63;
    const int srow  = t >> 6;

    const float4* xb = x + (size_t)b * (HW_POS * NCG);
    const int s0 = chunk * POS_PER_BLOCK;

    float4 s = make_float4(0.f, 0.f, 0.f, 0.f);
    float4 q = make_float4(0.f, 0.f, 0.f, 0.f);
    #pragma unroll 8
    for (int si = s0 + srow; si < s0 + POS_PER_BLOCK; si += 4) {
        float4 v = xb[(size_t)si * NCG + cg];
        s.x += v.x; s.y += v.y; s.z += v.z; s.w += v.w;
        q.x += v.x * v.x; q.y += v.y * v.y; q.z += v.z * v.z; q.w += v.w * v.w;
    }

    __shared__ float4 ls[4][64];
    __shared__ float4 lq[4][64];
    ls[srow][cg] = s;
    lq[srow][cg] = q;
    __syncthreads();

    if (srow == 0) {
        float4 a0 = ls[0][cg], a1 = ls[1][cg], a2 = ls[2][cg], a3 = ls[3][cg];
        float4 b0 = lq[0][cg], b1 = lq[1][cg], b2 = lq[2][cg], b3 = lq[3][cg];
        float ts[4] = { a0.x + a1.x + a2.x + a3.x,
                        a0.y + a1.y + a2.y + a3.y,
                        a0.z + a1.z + a2.z + a3.z,
                        a0.w + a1.w + a2.w + a3.w };
        float tq[4] = { b0.x + b1.x + b2.x + b3.x,
                        b0.y + b1.y + b2.y + b3.y,
                        b0.z + b1.z + b2.z + b3.z,
                        b0.w + b1.w + b2.w + b3.w };
        float* sp = asum + p * NCH + cg * 4;
        float* qp = asq  + p * NCH + cg * 4;
        #pragma unroll
        for (int k = 0; k < 4; ++k) {
            atomicAdd(sp + k, ts[k]);
            atomicAdd(qp + k, tq[k]);
        }
    }
}

// ---------------- Kernel 2: normalize (scale/shift computed inline) ----------
// Blocks walk in REVERSE order vs k_partial so the L3-resident tail of x is
// re-read first. Shuffle/unshuffle cancels: read & write image b = perm[j]
// in place, with partition p = j>>6 stats.
__global__ __launch_bounds__(256) void k_norm(const float4* __restrict__ x,
                                              const float* __restrict__ asum,
                                              const float* __restrict__ asq,
                                              const float* __restrict__ gamma,
                                              const float* __restrict__ beta,
                                              const int* __restrict__ perm,
                                              float4* __restrict__ out) {
    const int blk   = (int)gridDim.x - 1 - (int)blockIdx.x;   // reverse order
    const int j     = blk >> 2;
    const int chunk = blk & (SPLIT - 1);
    const int b     = perm[j];
    const int p     = j >> 6;
    const int t     = threadIdx.x;
    const int cg    = t & 63;
    const int srow  = t >> 6;

    // Per-thread fused affine coefficients for its 4 channels (L2-hit loads).
    float4 sc, sh;
    {
        float scv[4], shv[4];
        #pragma unroll
        for (int k = 0; k < 4; ++k) {
            const int c   = cg * 4 + k;
            const float s = asum[p * NCH + c];
            const float q = asq [p * NCH + c];
            const float mean = s * (1.0f / N_PER_PC);
            const float var  = q * (1.0f / N_PER_PC) - mean * mean;
            const float inv  = rsqrtf(var + EPS);
            const float g    = gamma[p * NCH + c];
            scv[k] = g * inv;
            shv[k] = beta[p * NCH + c] - mean * scv[k];
        }
        sc = make_float4(scv[0], scv[1], scv[2], scv[3]);
        sh = make_float4(shv[0], shv[1], shv[2], shv[3]);
    }

    const float4* xb = x   + (size_t)b * (HW_POS * NCG);
    float4*       ob = out + (size_t)b * (HW_POS * NCG);
    const int s0 = chunk * POS_PER_BLOCK;

    #pragma unroll 8
    for (int si = s0 + srow; si < s0 + POS_PER_BLOCK; si += 4) {
        float4 v = xb[(size_t)si * NCG + cg];
        v.x = v.x * sc.x + sh.x;
        v.y = v.y * sc.y + sh.y;
        v.z = v.z * sc.z + sh.z;
        v.w = v.w * sc.w + sh.w;
        ob[(size_t)si * NCG + cg] = v;
    }
}

extern "C" void kernel_launch(void* const* d_in, const int* in_sizes, int n_in,
                              void* d_out, int out_size, void* d_ws, size_t ws_size,
                              hipStream_t stream) {
    const float* x     = (const float*)d_in[0];
    const float* gamma = (const float*)d_in[1];
    const float* beta  = (const float*)d_in[2];
    const int*   perm  = (const int*)d_in[3];
    float* out = (float*)d_out;

    // Workspace: acc = [asum (NP*NCH) | asq (NP*NCH)] = 8 KB, zeroed each call.
    float* asum = (float*)d_ws;
    float* asq  = asum + NP * NCH;

    k_zero<<<1, 256, 0, stream>>>(asum);
    k_partial<<<NB * SPLIT, 256, 0, stream>>>((const float4*)x, perm, asum, asq);
    k_norm<<<NB * SPLIT, 256, 0, stream>>>((const float4*)x, asum, asq,
                                           gamma, beta, perm, (float4*)out);
}